// Round 6
// baseline (500.318 us; speedup 1.0000x reference)
//
#include <hip/hip_runtime.h>

// CapsuleLayer — B=32, I=2048, N=32, D=32, ROUTINGS=3.
// v6: v5b + __launch_bounds__(1024, 4). Controlled single-change experiment.
//   v5b counters showed VGPR_Count=64 for a kernel whose live set is ~90-110
//   (24 prefetch + 32 acc + col[32] + temps): without a min-waves arg the
//   compiler's heuristic targeted 8 waves/SIMD -> 64-VGPR cap -> ~40
//   regs/thread spilled to scratch. The spill set (~16 MB across the grid)
//   is L2-RESIDENT, so it never appeared in FETCH/WRITE — but every col[]
//   use in routing became a ~200 cyc L2 round-trip on the critical chain
//   (the unexplained 2x between the DS/VALU model and measured 246 µs).
//   (1024, 4) = 4 waves/EU min for a 16-wave block -> VGPR cap 128 -> fits.
//   Everything else byte-identical to v5b.
//
//   Structure (verified): MFMA phase 1 (bf16), fragment maps m74/m101;
//   1024 thr = 16 waves, grid 256 (1 block/CU, LDS 140.5 KB), NI=8;
//   reg-prefetch of next-i operands across raw s_barrier+lgkmcnt barriers;
//   phase 2 = 1024 routing items, LDS broadcast-row gathers, summation
//   order identical to v3/v4/v5 (absmax 0.0078125 = 1 bf16 ULP).

#define IC 2048
#define NS 33                 // floats per n-row in LDS (pad +1)
#define UHW (32 * NS)         // 1056 floats per batch row
#define NI 8                  // capsules per block; grid = 2048/NI = 256

typedef __attribute__((ext_vector_type(8)))  __bf16 bf16x8;
typedef __attribute__((ext_vector_type(16))) float  f32x16;

__device__ __forceinline__ unsigned short f_to_bfbits(float f) {  // RNE
    unsigned u = __float_as_uint(f);
    u += 0x7FFFu + ((u >> 16) & 1u);
    return (unsigned short)(u >> 16);
}
__device__ __forceinline__ void bar_lgkm() {
    // LDS-only drain + barrier: leaves global prefetch (vmcnt) in flight.
    asm volatile("s_waitcnt lgkmcnt(0)" ::: "memory");
    __builtin_amdgcn_s_barrier();
}

// ---- phase 2: one routing item (b, s). ub = uh[b]; olr/clr = ol[b]/cl[b].
// Summation order matches v3/v4/v5 exactly.
__device__ __forceinline__ float route_item(
    const float* __restrict__ ub, float* __restrict__ olr,
    float* __restrict__ clr, unsigned s)
{
    float col[32];   // U[b, n, d=s]
    #pragma unroll
    for (int nn = 0; nn < 32; ++nn) col[nn] = ub[nn * NS + s];

    float a = 0.f;
    #pragma unroll
    for (int nn = 0; nn < 32; ++nn) a += col[nn];
    float o = fmaxf(a * (1.0f / 32.0f), 0.f);

    olr[s] = o;                          // wave-local row: no barrier needed
    float r = 0.f;
    #pragma unroll
    for (int j = 0; j < 8; ++j) {
        const float4 og = *(const float4*)&olr[4 * j];
        const float4 rv = *(const float4*)&ub[s * NS + 4 * j];
        r += og.x * rv.x; r += og.y * rv.y; r += og.z * rv.z; r += og.w * rv.w;
    }

    #pragma unroll 1
    for (int iter = 1; iter < 3; ++iter) {
        float mx = r;
        #pragma unroll
        for (int off = 16; off >= 1; off >>= 1)
            mx = fmaxf(mx, __shfl_xor(mx, off, 32));
        const float e = __expf(r - mx);
        float sm = e;
        #pragma unroll
        for (int off = 16; off >= 1; off >>= 1)
            sm += __shfl_xor(sm, off, 32);
        const float c = e / sm;

        clr[s] = c;
        float t = 0.f;
        #pragma unroll
        for (int j = 0; j < 8; ++j) {
            const float4 cg = *(const float4*)&clr[4 * j];
            t += cg.x * col[4*j+0]; t += cg.y * col[4*j+1];
            t += cg.z * col[4*j+2]; t += cg.w * col[4*j+3];
        }
        o = fmaxf(t, 0.f);

        if (iter < 2) {
            olr[s] = o;
            float u = 0.f;
            #pragma unroll
            for (int j = 0; j < 8; ++j) {
                const float4 og = *(const float4*)&olr[4 * j];
                const float4 rv = *(const float4*)&ub[s * NS + 4 * j];
                u += og.x * rv.x; u += og.y * rv.y; u += og.z * rv.z; u += og.w * rv.w;
            }
            r += u;
        }
    }
    return o;
}

// ---- bf16 path: MFMA phase 1 ----
__device__ void body_bf16(
    const unsigned short* __restrict__ xb, const unsigned short* __restrict__ Wb,
    unsigned short* __restrict__ ob,
    float (*uh)[UHW], float (*ol)[32], float (*cl)[32],
    unsigned i0, unsigned tid)
{
    const unsigned lane = tid & 63, wid = tid >> 6;    // 16 waves
    const unsigned mrow = lane & 31;                   // A row / B col / D col
    const unsigned kh   = lane >> 5;                   // k-block (0/1)
    const unsigned b2   = tid >> 5, s2 = tid & 31;     // phase-2 item

    uint4 a0, a1, b00, b01, b10, b11;                  // current operands
    {
        const size_t xbase = ((size_t)mrow * IC + i0) * 32 + kh * 8;
        a0 = *(const uint4*)(xb + xbase);
        a1 = *(const uint4*)(xb + xbase + 16);
        const size_t wb = ((size_t)i0 * 1024 + wid * 64 + mrow) * 32 + kh * 8;
        b00 = *(const uint4*)(Wb + wb);
        b01 = *(const uint4*)(Wb + wb + 16);
        b10 = *(const uint4*)(Wb + wb + 1024);
        b11 = *(const uint4*)(Wb + wb + 1024 + 16);
    }

    #pragma unroll 1
    for (unsigned ii = 0; ii < NI; ++ii) {
        const unsigned i = i0 + ii;

        f32x16 acc0 = (f32x16)(0.0f);
        f32x16 acc1 = (f32x16)(0.0f);
        acc0 = __builtin_amdgcn_mfma_f32_32x32x16_bf16(
            __builtin_bit_cast(bf16x8, a0), __builtin_bit_cast(bf16x8, b00), acc0, 0, 0, 0);
        acc0 = __builtin_amdgcn_mfma_f32_32x32x16_bf16(
            __builtin_bit_cast(bf16x8, a1), __builtin_bit_cast(bf16x8, b01), acc0, 0, 0, 0);
        acc1 = __builtin_amdgcn_mfma_f32_32x32x16_bf16(
            __builtin_bit_cast(bf16x8, a0), __builtin_bit_cast(bf16x8, b10), acc1, 0, 0, 0);
        acc1 = __builtin_amdgcn_mfma_f32_32x32x16_bf16(
            __builtin_bit_cast(bf16x8, a1), __builtin_bit_cast(bf16x8, b11), acc1, 0, 0, 0);

        if (ii + 1 < NI) {   // prefetch i+1 operands; stays in flight thru phase 2
            const unsigned in = i + 1;
            const size_t xbase = ((size_t)mrow * IC + in) * 32 + kh * 8;
            a0 = *(const uint4*)(xb + xbase);
            a1 = *(const uint4*)(xb + xbase + 16);
            const size_t wb = ((size_t)in * 1024 + wid * 64 + mrow) * 32 + kh * 8;
            b00 = *(const uint4*)(Wb + wb);
            b01 = *(const uint4*)(Wb + wb + 16);
            b10 = *(const uint4*)(Wb + wb + 1024);
            b11 = *(const uint4*)(Wb + wb + 1024 + 16);
        }

        // D -> uh: col = mrow (d), n-tile = 2*wid (+1), row b per verified map
        const unsigned n0 = wid * 2;
        #pragma unroll
        for (int r = 0; r < 16; ++r) {
            const unsigned brow = (r & 3) + 8 * (r >> 2) + 4 * kh;
            uh[brow][n0 * NS + mrow]       = acc0[r];
            uh[brow][(n0 + 1) * NS + mrow] = acc1[r];
        }
        bar_lgkm();

        const float o = route_item(uh[b2], ol[b2], cl[b2], s2);
        ob[((size_t)b2 * IC + i) * 32 + s2] = f_to_bfbits(o);
        bar_lgkm();   // before next iter overwrites uh
    }
}

// ---- fp32 fallback: VALU phase 1 (correctness path; not the benched dtype)
__device__ void body_f32(
    const float* __restrict__ xf, const float* __restrict__ Wf,
    float* __restrict__ of,
    float (*uh)[UHW], float (*ol)[32], float (*cl)[32],
    unsigned i0, unsigned tid)
{
    const unsigned c = tid, n = c >> 5, d = c & 31;    // one c-row per thread
    const unsigned b2 = tid >> 5, s2 = tid & 31;

    #pragma unroll 1
    for (unsigned ii = 0; ii < NI; ++ii) {
        const unsigned i = i0 + ii;
        float w[32];
        {
            const float4* wr = (const float4*)(Wf + ((size_t)i * 1024 + c) * 32);
            #pragma unroll
            for (int j = 0; j < 8; ++j) {
                const float4 v = wr[j];
                w[4*j+0] = v.x; w[4*j+1] = v.y; w[4*j+2] = v.z; w[4*j+3] = v.w;
            }
        }
        #pragma unroll 2
        for (unsigned b = 0; b < 32; ++b) {
            const float4* xr = (const float4*)(xf + ((size_t)b * IC + i) * 32);
            float acc = 0.f;
            #pragma unroll
            for (int j = 0; j < 8; ++j) {
                const float4 v = xr[j];
                acc += v.x*w[4*j+0] + v.y*w[4*j+1] + v.z*w[4*j+2] + v.w*w[4*j+3];
            }
            uh[b][n * NS + d] = acc;
        }
        bar_lgkm();
        const float o = route_item(uh[b2], ol[b2], cl[b2], s2);
        of[((size_t)b2 * IC + i) * 32 + s2] = o;
        bar_lgkm();
    }
}

__global__ __launch_bounds__(1024, 4)   // 4 waves/EU min -> VGPR cap 128, no spill
void CapsuleLayer_72224170049868_kernel(
    const void* __restrict__ x, const void* __restrict__ W,
    void* __restrict__ out)
{
    __shared__ float uh[32][UHW];   // 132.0 KB
    __shared__ float ol[32][32];    // 4 KB (o broadcast rows)
    __shared__ float cl[32][32];    // 4 KB (c broadcast rows)
    __shared__ int   flagS;

    const unsigned tid = threadIdx.x;     // 0..1023
    const unsigned i0  = blockIdx.x * NI; // 256 blocks x 8 capsules

    // dtype sniff: bf16 even-halfword exponents are <=125 for |W|<0.5;
    // fp32 buffers put random mantissa bits there -> >=126 appears fast.
    if (tid == 0) {
        int f = 0;
        const unsigned* Wu_ = (const unsigned*)W;
        for (int j = 0; j < 32; ++j)
            if (((Wu_[j] >> 7) & 0xFFu) >= 126u) f = 1;
        flagS = f;
    }
    __syncthreads();
    const bool is_fp32 = (flagS != 0);

    if (is_fp32)
        body_f32((const float*)x, (const float*)W, (float*)out,
                 uh, ol, cl, i0, tid);
    else
        body_bf16((const unsigned short*)x, (const unsigned short*)W,
                  (unsigned short*)out, uh, ol, cl, i0, tid);
}

extern "C" void kernel_launch(void* const* d_in, const int* in_sizes, int n_in,
                              void* d_out, int out_size, void* d_ws, size_t ws_size,
                              hipStream_t stream) {
    (void)d_ws; (void)ws_size; (void)out_size;
    // defensive input-order detection: x = 2,097,152 elems, W = 67,108,864
    const int swap = (n_in >= 2 && in_sizes[0] > in_sizes[1]) ? 1 : 0;
    const void* x = d_in[swap ? 1 : 0];
    const void* W = d_in[swap ? 0 : 1];

    CapsuleLayer_72224170049868_kernel<<<dim3(IC / NI), dim3(1024), 0, stream>>>(x, W, d_out);
}